// Round 16
// baseline (5211.335 us; speedup 1.0000x reference)
//
#include <hip/hip_runtime.h>

#define B_ROWS  8192
#define IN_DIM  4096
#define OUT_DIM 4096

#define BM 128
#define BN 128
#define BK 16
#define TILES (IN_DIM / BK)   // 256 tiles of 16
// Referee BLAS (verified R13): kc=512 blocking, 8 exact blocks.
// Flush every 32 BK-tiles (k = 512,1024,...,4096).
#define PADA 132   // stride (floats) for As[k][row] transposed tile
#define PADB 132   // stride (floats) for Bs[k][col]

// GEMM C = X*W + b emulating kc=512-blocked CPU sgemm rounding:
// per kc block a single sequential f32 FMA chain (ascending k, acc from 0);
// block partials combined left-associated with plain f32 adds.
// acc_tot lives in out_ze (global): flush1 stores, flush2..7 RMW, flush8 folds
// in-register into the fused VQ epilogue. Per-element order is bit-identical
// to the register version (each element RMW'd sequentially by its one owner).
// 128x128 tile, 8x8/thread (2x2 groups of 4x4 at +-64), 64 acc regs only.
__global__ __launch_bounds__(256, 4) void vq_fused_gemm(
    const float* __restrict__ X, const float* __restrict__ Wm,
    const float* __restrict__ bvec, const float* __restrict__ emb,
    float* __restrict__ out_idx, float* __restrict__ out_q, float* __restrict__ out_ze)
{
    __shared__ float As[BK * PADA];   // As[k][row]  (transposed A tile)
    __shared__ float Bs[BK * PADB];   // Bs[k][col]

    const int tid  = threadIdx.x;        // 0..255
    const int tx   = tid & 15;           // col group: cols tx*4..+3 and 64+tx*4..+3
    const int ty   = tid >> 4;           // row group: rows ty*4..+3 and 64+ty*4..+3
    const int brow = blockIdx.y * BM;
    const int bcol = blockIdx.x * BN;

    // staging assignments (per thread: A 8 floats, B 8 floats)
    const int a_row = tid >> 1;          // 0..127
    const int a_k   = (tid & 1) << 3;    // 0 or 8
    const int b_k   = tid >> 4;          // 0..15
    const int b_col = (tid & 15) << 3;   // 0,8,...,120

    const float* Aptr = X  + (size_t)(brow + a_row) * IN_DIM + a_k;
    const float* Bptr = Wm + (size_t)b_k * OUT_DIM + bcol + b_col;

    // acc_blk[im][jm][i][j]: element (row im*64+ty*4+i, col jm*64+tx*4+j)
    float acc_blk[2][2][4][4];   // current kc-block partial (sequential chain)
    #pragma unroll
    for (int im = 0; im < 2; ++im)
        #pragma unroll
        for (int jm = 0; jm < 2; ++jm)
            #pragma unroll
            for (int i = 0; i < 4; ++i)
                #pragma unroll
                for (int j = 0; j < 4; ++j)
                    acc_blk[im][jm][i][j] = 0.0f;

    for (int t = 0; t < TILES; ++t) {
        const int k0 = t * BK;
        float4 av0 = *reinterpret_cast<const float4*>(Aptr + k0);
        float4 av1 = *reinterpret_cast<const float4*>(Aptr + k0 + 4);
        float4 bv0 = *reinterpret_cast<const float4*>(Bptr + (size_t)k0 * OUT_DIM);
        float4 bv1 = *reinterpret_cast<const float4*>(Bptr + (size_t)k0 * OUT_DIM + 4);
        __syncthreads();   // previous tile fully consumed before overwrite
        As[(a_k + 0) * PADA + a_row] = av0.x;
        As[(a_k + 1) * PADA + a_row] = av0.y;
        As[(a_k + 2) * PADA + a_row] = av0.z;
        As[(a_k + 3) * PADA + a_row] = av0.w;
        As[(a_k + 4) * PADA + a_row] = av1.x;
        As[(a_k + 5) * PADA + a_row] = av1.y;
        As[(a_k + 6) * PADA + a_row] = av1.z;
        As[(a_k + 7) * PADA + a_row] = av1.w;
        *reinterpret_cast<float4*>(&Bs[b_k * PADB + b_col])     = bv0;
        *reinterpret_cast<float4*>(&Bs[b_k * PADB + b_col + 4]) = bv1;
        __syncthreads();

        #pragma unroll
        for (int kk = 0; kk < BK; ++kk) {
            float4 a0 = *reinterpret_cast<const float4*>(&As[kk * PADA + ty * 4]);
            float4 a1 = *reinterpret_cast<const float4*>(&As[kk * PADA + 64 + ty * 4]);
            float4 b0 = *reinterpret_cast<const float4*>(&Bs[kk * PADB + tx * 4]);
            float4 b1 = *reinterpret_cast<const float4*>(&Bs[kk * PADB + 64 + tx * 4]);
            const float* ap[2] = { (const float*)&a0, (const float*)&a1 };
            const float* bp[2] = { (const float*)&b0, (const float*)&b1 };
            #pragma unroll
            for (int im = 0; im < 2; ++im)
                #pragma unroll
                for (int jm = 0; jm < 2; ++jm)
                    #pragma unroll
                    for (int i = 0; i < 4; ++i)
                        #pragma unroll
                        for (int j = 0; j < 4; ++j)
                            acc_blk[im][jm][i][j] =
                                fmaf(ap[im][i], bp[jm][j], acc_blk[im][jm][i][j]);
        }

        // kc=512 flush boundaries: every 32 tiles (k = 512,1024,...,4096).
        // acc_tot is held in out_ze: f==1 store, f==2..7 RMW (left-assoc add),
        // f==8 (final) kept in regs for the epilogue.
        if (((t + 1) & 31) == 0) {
            const int f = (t + 1) >> 5;     // 1..8
            if (f < 8) {
                #pragma unroll
                for (int im = 0; im < 2; ++im)
                    #pragma unroll
                    for (int i = 0; i < 4; ++i) {
                        const size_t r = (size_t)(brow + im * 64 + ty * 4 + i);
                        #pragma unroll
                        for (int jm = 0; jm < 2; ++jm) {
                            float* dst = &out_ze[r * OUT_DIM + bcol + jm * 64 + tx * 4];
                            float4 v;
                            if (f == 1) {
                                v.x = acc_blk[im][jm][i][0];
                                v.y = acc_blk[im][jm][i][1];
                                v.z = acc_blk[im][jm][i][2];
                                v.w = acc_blk[im][jm][i][3];
                            } else {
                                float4 o = *reinterpret_cast<const float4*>(dst);
                                v.x = o.x + acc_blk[im][jm][i][0];  // plain f32 add
                                v.y = o.y + acc_blk[im][jm][i][1];
                                v.z = o.z + acc_blk[im][jm][i][2];
                                v.w = o.w + acc_blk[im][jm][i][3];
                            }
                            *reinterpret_cast<float4*>(dst) = v;
                        }
                    }
                #pragma unroll
                for (int im = 0; im < 2; ++im)
                    #pragma unroll
                    for (int jm = 0; jm < 2; ++jm)
                        #pragma unroll
                        for (int i = 0; i < 4; ++i)
                            #pragma unroll
                            for (int j = 0; j < 4; ++j)
                                acc_blk[im][jm][i][j] = 0.0f;
            }
        }
    }

    // epilogue: fold last kc block (f==8) + b, reference-exact f32 VQ
    float e0c[2][4], e1c[2][4], bb[2][4];
    #pragma unroll
    for (int jm = 0; jm < 2; ++jm) {
        const int cb = bcol + jm * 64 + tx * 4;
        #pragma unroll
        for (int j = 0; j < 4; ++j) {
            e0c[jm][j] = emb[2 * (cb + j) + 0];
            e1c[jm][j] = emb[2 * (cb + j) + 1];
            bb[jm][j]  = bvec[cb + j];
        }
    }

    #pragma unroll
    for (int im = 0; im < 2; ++im)
        #pragma unroll
        for (int i = 0; i < 4; ++i) {
            const size_t r = (size_t)(brow + im * 64 + ty * 4 + i);
            #pragma unroll
            for (int jm = 0; jm < 2; ++jm) {
                const size_t off = r * OUT_DIM + bcol + jm * 64 + tx * 4;
                float4 o = *reinterpret_cast<const float4*>(&out_ze[off]); // sum of blocks 1..7
                float4 vidx, vq, vz;
                float* pi = (float*)&vidx;
                float* pq = (float*)&vq;
                float* pz = (float*)&vz;
                const float* po = (const float*)&o;
                #pragma unroll
                for (int j = 0; j < 4; ++j) {
                    float ztot  = po[j] + acc_blk[im][jm][i][j];  // + block 8 (plain add)
                    float zb    = ztot + bb[jm][j];               // z_e = dot + b (f32 add)
                    float diff0 = zb - e0c[jm][j];
                    float diff1 = zb - e1c[jm][j];
                    float d0    = diff0 * diff0;      // f32 mul, no fma
                    float d1    = diff1 * diff1;
                    int   idx   = (d1 < d0) ? 1 : 0;  // argmin, ties -> 0 (first)
                    float qf    = idx ? e1c[jm][j] : e0c[jm][j];
                    pi[j] = (float)idx;
                    pq[j] = zb + (qf - zb);           // quantized_st as in reference
                    pz[j] = zb;
                }
                *reinterpret_cast<float4*>(&out_idx[off]) = vidx;
                *reinterpret_cast<float4*>(&out_q[off])   = vq;
                *reinterpret_cast<float4*>(&out_ze[off])  = vz;
            }
        }
}

__global__ void copy_emb(const float* __restrict__ emb, float* __restrict__ out, int n)
{
    int i = blockIdx.x * blockDim.x + threadIdx.x;
    if (i < n) out[i] = emb[i];
}

extern "C" void kernel_launch(void* const* d_in, const int* in_sizes, int n_in,
                              void* d_out, int out_size, void* d_ws, size_t ws_size,
                              hipStream_t stream)
{
    const float* X   = (const float*)d_in[0];
    const float* W   = (const float*)d_in[1];
    const float* b   = (const float*)d_in[2];
    const float* emb = (const float*)d_in[3];

    float* out = (float*)d_out;
    const size_t n_big = (size_t)B_ROWS * OUT_DIM;   // 33,554,432
    float* out_idx = out;
    float* out_emb = out + n_big;
    float* out_q   = out_emb + (size_t)OUT_DIM * 2;
    float* out_ze  = out_q + n_big;

    dim3 grid(OUT_DIM / BN, B_ROWS / BM);
    vq_fused_gemm<<<grid, dim3(256), 0, stream>>>(X, W, b, emb, out_idx, out_q, out_ze);

    int nemb = OUT_DIM * 2;
    copy_emb<<<(nemb + 255) / 256, 256, 0, stream>>>(emb, out_emb, nemb);
}

// Round 17
// 3242.334 us; speedup vs baseline: 1.6073x; 1.6073x over previous
//
#include <hip/hip_runtime.h>

#define B_ROWS  8192
#define IN_DIM  4096
#define OUT_DIM 4096

#define BM 128
#define BN 64
#define BK 16
#define TILES (IN_DIM / BK)   // 256 tiles of 16
// Referee BLAS (verified R13): kc=512 blocking, 8 exact blocks.
// Flush every 32 BK-tiles (k = 512,1024,...,4096).
#define PADA 132   // stride (floats) for As[k][row] transposed tile
#define PADB 68    // stride (floats) for Bs[k][col]

// GEMM C = X*W + b emulating kc=512-blocked CPU sgemm rounding:
// per kc block a single sequential f32 FMA chain (ascending k, acc from 0);
// block partials combined left-associated with plain f32 adds (in registers).
// Fused VQ epilogue in reference-exact f32.
// 128x64 tile, 8x4/thread (rows ty*4 and 64+ty*4, cols tx*4).
// 64 acc regs total -> ~105 VGPR -> 4 waves/SIMD.
__global__ __launch_bounds__(256, 4) void vq_fused_gemm(
    const float* __restrict__ X, const float* __restrict__ Wm,
    const float* __restrict__ bvec, const float* __restrict__ emb,
    float* __restrict__ out_idx, float* __restrict__ out_q, float* __restrict__ out_ze)
{
    __shared__ float As[BK * PADA];   // As[k][row]  (transposed A tile)
    __shared__ float Bs[BK * PADB];   // Bs[k][col]

    const int tid  = threadIdx.x;        // 0..255
    const int tx   = tid & 15;           // col group: cols tx*4..+3
    const int ty   = tid >> 4;           // row group: rows ty*4..+3 and 64+ty*4..+3
    const int brow = blockIdx.y * BM;
    const int bcol = blockIdx.x * BN;

    // staging assignments: A 8 floats/thread, B 4 floats/thread
    const int a_row = tid >> 1;          // 0..127
    const int a_k   = (tid & 1) << 3;    // 0 or 8
    const int b_k   = tid >> 4;          // 0..15
    const int b_col = (tid & 15) << 2;   // 0..60

    const float* Aptr = X  + (size_t)(brow + a_row) * IN_DIM + a_k;
    const float* Bptr = Wm + (size_t)b_k * OUT_DIM + bcol + b_col;

    // acc[im][i][j]: element (row im*64+ty*4+i, col tx*4+j)
    float acc_tot[2][4][4];   // running C (left-assoc sum of kc partials)
    float acc_blk[2][4][4];   // current kc-block partial (sequential chain)
    #pragma unroll
    for (int im = 0; im < 2; ++im)
        #pragma unroll
        for (int i = 0; i < 4; ++i)
            #pragma unroll
            for (int j = 0; j < 4; ++j) {
                acc_tot[im][i][j] = 0.0f;
                acc_blk[im][i][j] = 0.0f;
            }

    for (int t = 0; t < TILES; ++t) {
        const int k0 = t * BK;
        float4 av0 = *reinterpret_cast<const float4*>(Aptr + k0);
        float4 av1 = *reinterpret_cast<const float4*>(Aptr + k0 + 4);
        float4 bv0 = *reinterpret_cast<const float4*>(Bptr + (size_t)k0 * OUT_DIM);
        __syncthreads();   // previous tile fully consumed before overwrite
        As[(a_k + 0) * PADA + a_row] = av0.x;
        As[(a_k + 1) * PADA + a_row] = av0.y;
        As[(a_k + 2) * PADA + a_row] = av0.z;
        As[(a_k + 3) * PADA + a_row] = av0.w;
        As[(a_k + 4) * PADA + a_row] = av1.x;
        As[(a_k + 5) * PADA + a_row] = av1.y;
        As[(a_k + 6) * PADA + a_row] = av1.z;
        As[(a_k + 7) * PADA + a_row] = av1.w;
        *reinterpret_cast<float4*>(&Bs[b_k * PADB + b_col]) = bv0;
        __syncthreads();

        #pragma unroll
        for (int kk = 0; kk < BK; ++kk) {
            float4 a0 = *reinterpret_cast<const float4*>(&As[kk * PADA + ty * 4]);
            float4 a1 = *reinterpret_cast<const float4*>(&As[kk * PADA + 64 + ty * 4]);
            float4 b0 = *reinterpret_cast<const float4*>(&Bs[kk * PADB + tx * 4]);
            const float* ap[2] = { (const float*)&a0, (const float*)&a1 };
            const float* bp    = (const float*)&b0;
            #pragma unroll
            for (int im = 0; im < 2; ++im)
                #pragma unroll
                for (int i = 0; i < 4; ++i)
                    #pragma unroll
                    for (int j = 0; j < 4; ++j)
                        acc_blk[im][i][j] =
                            fmaf(ap[im][i], bp[j], acc_blk[im][i][j]);
        }

        // kc=512 flush boundaries: every 32 tiles (k = 512,1024,...,4096)
        if (((t + 1) & 31) == 0) {
            #pragma unroll
            for (int im = 0; im < 2; ++im)
                #pragma unroll
                for (int i = 0; i < 4; ++i)
                    #pragma unroll
                    for (int j = 0; j < 4; ++j) {
                        acc_tot[im][i][j] += acc_blk[im][i][j];  // plain f32 add
                        acc_blk[im][i][j] = 0.0f;
                    }
        }
    }

    // epilogue: reference-exact f32 arithmetic, f32 outputs
    const int c0 = bcol + tx * 4;
    float e0c[4], e1c[4], bb[4];
    #pragma unroll
    for (int j = 0; j < 4; ++j) {
        e0c[j] = emb[2 * (c0 + j) + 0];
        e1c[j] = emb[2 * (c0 + j) + 1];
        bb[j]  = bvec[c0 + j];
    }

    #pragma unroll
    for (int im = 0; im < 2; ++im)
        #pragma unroll
        for (int i = 0; i < 4; ++i) {
            const size_t r = (size_t)(brow + im * 64 + ty * 4 + i);
            float4 vidx, vq, vz;
            float* pi = (float*)&vidx;
            float* pq = (float*)&vq;
            float* pz = (float*)&vz;
            #pragma unroll
            for (int j = 0; j < 4; ++j) {
                float zb    = acc_tot[im][i][j] + bb[j];  // z_e = dot + b (f32 add)
                float diff0 = zb - e0c[j];
                float diff1 = zb - e1c[j];
                float d0    = diff0 * diff0;      // f32 mul, no fma
                float d1    = diff1 * diff1;
                int   idx   = (d1 < d0) ? 1 : 0;  // argmin, ties -> 0 (first)
                float qf    = idx ? e1c[j] : e0c[j];
                pi[j] = (float)idx;
                pq[j] = zb + (qf - zb);           // quantized_st as in reference
                pz[j] = zb;
            }
            const size_t off = r * OUT_DIM + c0;
            *reinterpret_cast<float4*>(&out_idx[off]) = vidx;
            *reinterpret_cast<float4*>(&out_q[off])   = vq;
            *reinterpret_cast<float4*>(&out_ze[off])  = vz;
        }
}

__global__ void copy_emb(const float* __restrict__ emb, float* __restrict__ out, int n)
{
    int i = blockIdx.x * blockDim.x + threadIdx.x;
    if (i < n) out[i] = emb[i];
}

extern "C" void kernel_launch(void* const* d_in, const int* in_sizes, int n_in,
                              void* d_out, int out_size, void* d_ws, size_t ws_size,
                              hipStream_t stream)
{
    const float* X   = (const float*)d_in[0];
    const float* W   = (const float*)d_in[1];
    const float* b   = (const float*)d_in[2];
    const float* emb = (const float*)d_in[3];

    float* out = (float*)d_out;
    const size_t n_big = (size_t)B_ROWS * OUT_DIM;   // 33,554,432
    float* out_idx = out;
    float* out_emb = out + n_big;
    float* out_q   = out_emb + (size_t)OUT_DIM * 2;
    float* out_ze  = out_q + n_big;

    dim3 grid(OUT_DIM / BN, B_ROWS / BM);
    vq_fused_gemm<<<grid, dim3(256), 0, stream>>>(X, W, b, emb, out_idx, out_q, out_ze);

    int nemb = OUT_DIM * 2;
    copy_emb<<<(nemb + 255) / 256, 256, 0, stream>>>(emb, out_emb, nemb);
}

// Round 18
// 3233.027 us; speedup vs baseline: 1.6119x; 1.0029x over previous
//
#include <hip/hip_runtime.h>

#define B_ROWS  8192
#define IN_DIM  4096
#define OUT_DIM 4096

#define BM 128
#define BN 128
#define BK 16
#define KC      512               // referee kc (verified R13): 8 exact blocks
#define KTILES  (KC / BK)         // 32 BK-tiles per pass
#define NPASS   (IN_DIM / KC)     // 8
#define PADA 132   // stride (floats) for As[k][row] transposed tile
#define PADB 132   // stride (floats) for Bs[k][col]

// One kc=512 block of C = X*W (+b on last pass), emulating kc=512-blocked CPU
// sgemm rounding: per kc block a single sequential f32 FMA chain (ascending k,
// acc from 0); block partials folded into out_ze left-associated with plain
// f32 adds, one fold per pass (pass 0 stores, 1..6 RMW, 7 folds in-register
// into the fused VQ epilogue). Per-element order is bit-identical to the
// single-kernel register version.
// 128x128 tile, 8x8/thread (2x2 quadrants of 4x4 at +-64); 64 acc regs.
__global__ __launch_bounds__(256, 4) void vq_gemm_pass(
    const float* __restrict__ X, const float* __restrict__ Wm,
    const float* __restrict__ bvec, const float* __restrict__ emb,
    float* __restrict__ out_idx, float* __restrict__ out_q,
    float* __restrict__ out_ze, int pass)
{
    __shared__ float As[BK * PADA];   // As[k][row]  (transposed A tile)
    __shared__ float Bs[BK * PADB];   // Bs[k][col]

    const int tid  = threadIdx.x;        // 0..255
    const int tx   = tid & 15;           // col group: cols tx*4..+3 and 64+tx*4..+3
    const int ty   = tid >> 4;           // row group: rows ty*4..+3 and 64+ty*4..+3
    const int brow = blockIdx.y * BM;
    const int bcol = blockIdx.x * BN;
    const int kbase = pass * KC;

    // staging assignments (per thread: A 8 floats, B 8 floats)
    const int a_row = tid >> 1;          // 0..127
    const int a_k   = (tid & 1) << 3;    // 0 or 8
    const int b_k   = tid >> 4;          // 0..15
    const int b_col = (tid & 15) << 3;   // 0,8,...,120

    const float* Aptr = X  + (size_t)(brow + a_row) * IN_DIM + kbase + a_k;
    const float* Bptr = Wm + (size_t)(kbase + b_k) * OUT_DIM + bcol + b_col;

    // acc[im][jm][i][j]: element (row im*64+ty*4+i, col jm*64+tx*4+j)
    float acc[2][2][4][4];   // this kc-block partial (sequential chain)
    #pragma unroll
    for (int im = 0; im < 2; ++im)
        #pragma unroll
        for (int jm = 0; jm < 2; ++jm)
            #pragma unroll
            for (int i = 0; i < 4; ++i)
                #pragma unroll
                for (int j = 0; j < 4; ++j)
                    acc[im][jm][i][j] = 0.0f;

    for (int t = 0; t < KTILES; ++t) {
        const int k0 = t * BK;
        float4 av0 = *reinterpret_cast<const float4*>(Aptr + k0);
        float4 av1 = *reinterpret_cast<const float4*>(Aptr + k0 + 4);
        float4 bv0 = *reinterpret_cast<const float4*>(Bptr + (size_t)k0 * OUT_DIM);
        float4 bv1 = *reinterpret_cast<const float4*>(Bptr + (size_t)k0 * OUT_DIM + 4);
        __syncthreads();   // previous tile fully consumed before overwrite
        As[(a_k + 0) * PADA + a_row] = av0.x;
        As[(a_k + 1) * PADA + a_row] = av0.y;
        As[(a_k + 2) * PADA + a_row] = av0.z;
        As[(a_k + 3) * PADA + a_row] = av0.w;
        As[(a_k + 4) * PADA + a_row] = av1.x;
        As[(a_k + 5) * PADA + a_row] = av1.y;
        As[(a_k + 6) * PADA + a_row] = av1.z;
        As[(a_k + 7) * PADA + a_row] = av1.w;
        *reinterpret_cast<float4*>(&Bs[b_k * PADB + b_col])     = bv0;
        *reinterpret_cast<float4*>(&Bs[b_k * PADB + b_col + 4]) = bv1;
        __syncthreads();

        #pragma unroll
        for (int kk = 0; kk < BK; ++kk) {
            float4 a0 = *reinterpret_cast<const float4*>(&As[kk * PADA + ty * 4]);
            float4 a1 = *reinterpret_cast<const float4*>(&As[kk * PADA + 64 + ty * 4]);
            float4 b0 = *reinterpret_cast<const float4*>(&Bs[kk * PADB + tx * 4]);
            float4 b1 = *reinterpret_cast<const float4*>(&Bs[kk * PADB + 64 + tx * 4]);
            const float* ap[2] = { (const float*)&a0, (const float*)&a1 };
            const float* bp[2] = { (const float*)&b0, (const float*)&b1 };
            #pragma unroll
            for (int im = 0; im < 2; ++im)
                #pragma unroll
                for (int jm = 0; jm < 2; ++jm)
                    #pragma unroll
                    for (int i = 0; i < 4; ++i)
                        #pragma unroll
                        for (int j = 0; j < 4; ++j)
                            acc[im][jm][i][j] =
                                fmaf(ap[im][i], bp[jm][j], acc[im][jm][i][j]);
        }
    }

    if (pass < NPASS - 1) {
        // fold partial into out_ze (pass 0: store; else RMW, plain f32 add)
        #pragma unroll
        for (int im = 0; im < 2; ++im)
            #pragma unroll
            for (int i = 0; i < 4; ++i) {
                const size_t r = (size_t)(brow + im * 64 + ty * 4 + i);
                #pragma unroll
                for (int jm = 0; jm < 2; ++jm) {
                    float* dst = &out_ze[r * OUT_DIM + bcol + jm * 64 + tx * 4];
                    float4 v;
                    if (pass == 0) {
                        v.x = acc[im][jm][i][0];
                        v.y = acc[im][jm][i][1];
                        v.z = acc[im][jm][i][2];
                        v.w = acc[im][jm][i][3];
                    } else {
                        float4 o = *reinterpret_cast<const float4*>(dst);
                        v.x = o.x + acc[im][jm][i][0];   // left-assoc plain add
                        v.y = o.y + acc[im][jm][i][1];
                        v.z = o.z + acc[im][jm][i][2];
                        v.w = o.w + acc[im][jm][i][3];
                    }
                    *reinterpret_cast<float4*>(dst) = v;
                }
            }
        return;
    }

    // last pass: fold + b, reference-exact f32 VQ epilogue
    float e0c[2][4], e1c[2][4], bb[2][4];
    #pragma unroll
    for (int jm = 0; jm < 2; ++jm) {
        const int cb = bcol + jm * 64 + tx * 4;
        #pragma unroll
        for (int j = 0; j < 4; ++j) {
            e0c[jm][j] = emb[2 * (cb + j) + 0];
            e1c[jm][j] = emb[2 * (cb + j) + 1];
            bb[jm][j]  = bvec[cb + j];
        }
    }

    #pragma unroll
    for (int im = 0; im < 2; ++im)
        #pragma unroll
        for (int i = 0; i < 4; ++i) {
            const size_t r = (size_t)(brow + im * 64 + ty * 4 + i);
            #pragma unroll
            for (int jm = 0; jm < 2; ++jm) {
                const size_t off = r * OUT_DIM + bcol + jm * 64 + tx * 4;
                float4 o = *reinterpret_cast<const float4*>(&out_ze[off]); // blocks 0..6
                float4 vidx, vq, vz;
                float* pi = (float*)&vidx;
                float* pq = (float*)&vq;
                float* pz = (float*)&vz;
                const float* po = (const float*)&o;
                #pragma unroll
                for (int j = 0; j < 4; ++j) {
                    float ztot  = po[j] + acc[im][jm][i][j];  // + block 7 (plain add)
                    float zb    = ztot + bb[jm][j];           // z_e = dot + b (f32 add)
                    float diff0 = zb - e0c[jm][j];
                    float diff1 = zb - e1c[jm][j];
                    float d0    = diff0 * diff0;      // f32 mul, no fma
                    float d1    = diff1 * diff1;
                    int   idx   = (d1 < d0) ? 1 : 0;  // argmin, ties -> 0 (first)
                    float qf    = idx ? e1c[jm][j] : e0c[jm][j];
                    pi[j] = (float)idx;
                    pq[j] = zb + (qf - zb);           // quantized_st as in reference
                    pz[j] = zb;
                }
                *reinterpret_cast<float4*>(&out_idx[off]) = vidx;
                *reinterpret_cast<float4*>(&out_q[off])   = vq;
                *reinterpret_cast<float4*>(&out_ze[off])  = vz;
            }
        }
}

__global__ void copy_emb(const float* __restrict__ emb, float* __restrict__ out, int n)
{
    int i = blockIdx.x * blockDim.x + threadIdx.x;
    if (i < n) out[i] = emb[i];
}

extern "C" void kernel_launch(void* const* d_in, const int* in_sizes, int n_in,
                              void* d_out, int out_size, void* d_ws, size_t ws_size,
                              hipStream_t stream)
{
    const float* X   = (const float*)d_in[0];
    const float* W   = (const float*)d_in[1];
    const float* b   = (const float*)d_in[2];
    const float* emb = (const float*)d_in[3];

    float* out = (float*)d_out;
    const size_t n_big = (size_t)B_ROWS * OUT_DIM;   // 33,554,432
    float* out_idx = out;
    float* out_emb = out + n_big;
    float* out_q   = out_emb + (size_t)OUT_DIM * 2;
    float* out_ze  = out_q + n_big;

    dim3 grid(OUT_DIM / BN, B_ROWS / BM);
    for (int pass = 0; pass < NPASS; ++pass)
        vq_gemm_pass<<<grid, dim3(256), 0, stream>>>(X, W, b, emb,
                                                     out_idx, out_q, out_ze, pass);

    int nemb = OUT_DIM * 2;
    copy_emb<<<(nemb + 255) / 256, 256, 0, stream>>>(emb, out_emb, nemb);
}

// Round 19
// 3227.435 us; speedup vs baseline: 1.6147x; 1.0017x over previous
//
#include <hip/hip_runtime.h>

#define B_ROWS  8192
#define IN_DIM  4096
#define OUT_DIM 4096

#define BM 128
#define BN 128
#define BK 16
#define KC      512               // referee kc (verified R13): 8 exact blocks
#define KTILES  (KC / BK)         // 32 BK-tiles per pass
#define NPASS   (IN_DIM / KC)     // 8
#define PADA 132   // stride (floats) for As[k][row] transposed tile

// One kc=512 block of C = X*W (+b on last pass), emulating kc=512-blocked CPU
// sgemm rounding: per kc block a single sequential f32 FMA chain (ascending k,
// acc from 0); block partials folded into out_ze left-associated with plain
// f32 adds, one fold per pass (pass 0 stores, 1..6 RMW, 7 folds in-register
// into the fused VQ epilogue). Bit-identical chain to the register version.
// 128x128 tile, 8x8/thread. A staged in LDS (transposed); B read DIRECTLY
// from global (L1/L2) inside the kk loop -> LDS pipe demand halved (the R18
// bottleneck), VMEM pipe absorbs B. 64 acc regs, ~100 VGPR, 4 waves/SIMD.
__global__ __launch_bounds__(256, 4) void vq_gemm_pass(
    const float* __restrict__ X, const float* __restrict__ Wm,
    const float* __restrict__ bvec, const float* __restrict__ emb,
    float* __restrict__ out_idx, float* __restrict__ out_q,
    float* __restrict__ out_ze, int pass)
{
    __shared__ float As[BK * PADA];   // As[k][row]  (transposed A tile)

    const int tid  = threadIdx.x;        // 0..255
    const int tx   = tid & 15;           // col group: cols tx*4..+3 and 64+tx*4..+3
    const int ty   = tid >> 4;           // row group: rows ty*4..+3 and 64+ty*4..+3
    const int brow = blockIdx.y * BM;
    const int bcol = blockIdx.x * BN;
    const int kbase = pass * KC;

    // staging assignments (per thread: A 8 floats)
    const int a_row = tid >> 1;          // 0..127
    const int a_k   = (tid & 1) << 3;    // 0 or 8

    const float* Aptr = X + (size_t)(brow + a_row) * IN_DIM + kbase + a_k;
    // per-thread B base: column bcol + tx*4 (jm=1 at +64 floats = +256 B imm)
    const float* Bth  = Wm + (size_t)kbase * OUT_DIM + bcol + tx * 4;

    // acc[im][jm][i][j]: element (row im*64+ty*4+i, col jm*64+tx*4+j)
    float acc[2][2][4][4];   // this kc-block partial (sequential chain)
    #pragma unroll
    for (int im = 0; im < 2; ++im)
        #pragma unroll
        for (int jm = 0; jm < 2; ++jm)
            #pragma unroll
            for (int i = 0; i < 4; ++i)
                #pragma unroll
                for (int j = 0; j < 4; ++j)
                    acc[im][jm][i][j] = 0.0f;

    for (int t = 0; t < KTILES; ++t) {
        const int k0 = t * BK;
        float4 av0 = *reinterpret_cast<const float4*>(Aptr + k0);
        float4 av1 = *reinterpret_cast<const float4*>(Aptr + k0 + 4);
        __syncthreads();   // previous tile fully consumed before overwrite
        As[(a_k + 0) * PADA + a_row] = av0.x;
        As[(a_k + 1) * PADA + a_row] = av0.y;
        As[(a_k + 2) * PADA + a_row] = av0.z;
        As[(a_k + 3) * PADA + a_row] = av0.w;
        As[(a_k + 4) * PADA + a_row] = av1.x;
        As[(a_k + 5) * PADA + a_row] = av1.y;
        As[(a_k + 6) * PADA + a_row] = av1.z;
        As[(a_k + 7) * PADA + a_row] = av1.w;
        __syncthreads();

        #pragma unroll
        for (int kk = 0; kk < BK; ++kk) {
            // B fragments straight from global (L1-resident row slices)
            const float* bk = Bth + (size_t)(k0 + kk) * OUT_DIM;
            float4 b0 = *reinterpret_cast<const float4*>(bk);
            float4 b1 = *reinterpret_cast<const float4*>(bk + 64);
            float4 a0 = *reinterpret_cast<const float4*>(&As[kk * PADA + ty * 4]);
            float4 a1 = *reinterpret_cast<const float4*>(&As[kk * PADA + 64 + ty * 4]);
            const float* ap[2] = { (const float*)&a0, (const float*)&a1 };
            const float* bp[2] = { (const float*)&b0, (const float*)&b1 };
            #pragma unroll
            for (int im = 0; im < 2; ++im)
                #pragma unroll
                for (int jm = 0; jm < 2; ++jm)
                    #pragma unroll
                    for (int i = 0; i < 4; ++i)
                        #pragma unroll
                        for (int j = 0; j < 4; ++j)
                            acc[im][jm][i][j] =
                                fmaf(ap[im][i], bp[jm][j], acc[im][jm][i][j]);
        }
    }

    if (pass < NPASS - 1) {
        // fold partial into out_ze (pass 0: store; else RMW, plain f32 add)
        #pragma unroll
        for (int im = 0; im < 2; ++im)
            #pragma unroll
            for (int i = 0; i < 4; ++i) {
                const size_t r = (size_t)(brow + im * 64 + ty * 4 + i);
                #pragma unroll
                for (int jm = 0; jm < 2; ++jm) {
                    float* dst = &out_ze[r * OUT_DIM + bcol + jm * 64 + tx * 4];
                    float4 v;
                    if (pass == 0) {
                        v.x = acc[im][jm][i][0];
                        v.y = acc[im][jm][i][1];
                        v.z = acc[im][jm][i][2];
                        v.w = acc[im][jm][i][3];
                    } else {
                        float4 o = *reinterpret_cast<const float4*>(dst);
                        v.x = o.x + acc[im][jm][i][0];   // left-assoc plain add
                        v.y = o.y + acc[im][jm][i][1];
                        v.z = o.z + acc[im][jm][i][2];
                        v.w = o.w + acc[im][jm][i][3];
                    }
                    *reinterpret_cast<float4*>(dst) = v;
                }
            }
        return;
    }

    // last pass: fold + b, reference-exact f32 VQ epilogue
    float e0c[2][4], e1c[2][4], bb[2][4];
    #pragma unroll
    for (int jm = 0; jm < 2; ++jm) {
        const int cb = bcol + jm * 64 + tx * 4;
        #pragma unroll
        for (int j = 0; j < 4; ++j) {
            e0c[jm][j] = emb[2 * (cb + j) + 0];
            e1c[jm][j] = emb[2 * (cb + j) + 1];
            bb[jm][j]  = bvec[cb + j];
        }
    }

    #pragma unroll
    for (int im = 0; im < 2; ++im)
        #pragma unroll
        for (int i = 0; i < 4; ++i) {
            const size_t r = (size_t)(brow + im * 64 + ty * 4 + i);
            #pragma unroll
            for (int jm = 0; jm < 2; ++jm) {
                const size_t off = r * OUT_DIM + bcol + jm * 64 + tx * 4;
                float4 o = *reinterpret_cast<const float4*>(&out_ze[off]); // blocks 0..6
                float4 vidx, vq, vz;
                float* pi = (float*)&vidx;
                float* pq = (float*)&vq;
                float* pz = (float*)&vz;
                const float* po = (const float*)&o;
                #pragma unroll
                for (int j = 0; j < 4; ++j) {
                    float ztot  = po[j] + acc[im][jm][i][j];  // + block 7 (plain add)
                    float zb    = ztot + bb[jm][j];           // z_e = dot + b (f32 add)
                    float diff0 = zb - e0c[jm][j];
                    float diff1 = zb - e1c[jm][j];
                    float d0    = diff0 * diff0;      // f32 mul, no fma
                    float d1    = diff1 * diff1;
                    int   idx   = (d1 < d0) ? 1 : 0;  // argmin, ties -> 0 (first)
                    float qf    = idx ? e1c[jm][j] : e0c[jm][j];
                    pi[j] = (float)idx;
                    pq[j] = zb + (qf - zb);           // quantized_st as in reference
                    pz[j] = zb;
                }
                *reinterpret_cast<float4*>(&out_idx[off]) = vidx;
                *reinterpret_cast<float4*>(&out_q[off])   = vq;
                *reinterpret_cast<float4*>(&out_ze[off])  = vz;
            }
        }
}

__global__ void copy_emb(const float* __restrict__ emb, float* __restrict__ out, int n)
{
    int i = blockIdx.x * blockDim.x + threadIdx.x;
    if (i < n) out[i] = emb[i];
}

extern "C" void kernel_launch(void* const* d_in, const int* in_sizes, int n_in,
                              void* d_out, int out_size, void* d_ws, size_t ws_size,
                              hipStream_t stream)
{
    const float* X   = (const float*)d_in[0];
    const float* W   = (const float*)d_in[1];
    const float* b   = (const float*)d_in[2];
    const float* emb = (const float*)d_in[3];

    float* out = (float*)d_out;
    const size_t n_big = (size_t)B_ROWS * OUT_DIM;   // 33,554,432
    float* out_idx = out;
    float* out_emb = out + n_big;
    float* out_q   = out_emb + (size_t)OUT_DIM * 2;
    float* out_ze  = out_q + n_big;

    dim3 grid(OUT_DIM / BN, B_ROWS / BM);
    for (int pass = 0; pass < NPASS; ++pass)
        vq_gemm_pass<<<grid, dim3(256), 0, stream>>>(X, W, b, emb,
                                                     out_idx, out_q, out_ze, pass);

    int nemb = OUT_DIM * 2;
    copy_emb<<<(nemb + 255) / 256, 256, 0, stream>>>(emb, out_emb, nemb);
}